// Round 8
// baseline (787.539 us; speedup 1.0000x reference)
//
#include <hip/hip_runtime.h>
#include <math.h>

// Problem constants: B=8, N=1024, FIN=FOUT=512, H=8, HD=64, BH=64

typedef __attribute__((ext_vector_type(8))) short short8;    // 8 bf16 (4 VGPRs)
typedef __attribute__((ext_vector_type(4))) float floatx4;   // MFMA C/D

// Workspace byte offsets (~52 MB; vt overlays x-hi; psums overlay raw)
#define OB_XH   0ull          // 8388608 B  x hi bf16  (later: v^T bf16)
#define OB_XL   8388608ull    // 8388608 B  x lo bf16
#define OB_WP   16777216ull   // 1048576 B  W' fp32 (reused q/k/v)
#define OB_WPH  17825792ull   // 524288 B   W' hi bf16
#define OB_WPL  18350080ull   // 524288 B   W' lo bf16
#define OB_RAW  18874368ull   // 16777216 B raw projection fp32 (b,h,n,d)
#define OB_PS   OB_RAW        // 2097152 B  partial (m,l) x4 (overlays dead raw)
#define OB_QLV  35651584ull   // 8388608 B  q levels bf16
#define OB_KLV  44040192ull   // 8388608 B  k levels bf16
#define OB_RS   52428800ull   // 524288 B   rowstats float2
#define OB_BM   52953088ull   // 1048576 B  adj bitmask u64
#define OB_AMAX 54001664ull   // 16 B       amax_q, amax_k, amax_attn

__device__ __forceinline__ unsigned short bf16_rne(float f) {
    unsigned int u = __float_as_uint(f);
    unsigned int r = u + 0x7fffu + ((u >> 16) & 1u);
    return (unsigned short)(r >> 16);
}
__device__ __forceinline__ float bf16_to_f(unsigned short h) {
    return __uint_as_float(((unsigned int)h) << 16);
}
// exact for values already representable in bf16 (integer levels |x|<=127)
__device__ __forceinline__ unsigned short bf16_exact(float f) {
    return (unsigned short)(__float_as_uint(f) >> 16);
}

__device__ __forceinline__ void outer4(float (&acc)[4], float4 a4, float b0,
                                       float b1, float b2, float b3) {
    (void)a4; (void)b0; (void)b1; (void)b2; (void)b3; (void)acc;
}

// ---------------------------------------------------------------------------
// K0: adjacency (8,1024,1024) i32 -> bitmask (8,1024,16) u64. One word/wave.
// ---------------------------------------------------------------------------
__global__ __launch_bounds__(256) void adj_bits_k(
    const int* __restrict__ adj, unsigned long long* __restrict__ bm)
{
    int tid = threadIdx.x;
    int wv = tid >> 6, lane = tid & 63;
    size_t word = (size_t)blockIdx.x * 4 + wv;       // 131072 words total
    int a = adj[word * 64 + lane];
    unsigned long long m = __ballot(a != 0);
    if (lane == 0) bm[word] = m;
}

// ---------------------------------------------------------------------------
// K0b: fp32 -> bf16 hi/lo split (x; consumed only by the V projection).
// q/k projections stay fp32 for quant-boundary exactness.
// ---------------------------------------------------------------------------
__global__ __launch_bounds__(256) void split_hl_k(
    const float* __restrict__ src, unsigned short* __restrict__ hi,
    unsigned short* __restrict__ lo, int n4)
{
    int i = blockIdx.x * 256 + threadIdx.x;
    if (i >= n4) return;
    float4 v = ((const float4*)src)[i];
    ushort4 h, l;
    h.x = bf16_rne(v.x); l.x = bf16_rne(v.x - bf16_to_f(h.x));
    h.y = bf16_rne(v.y); l.y = bf16_rne(v.y - bf16_to_f(h.y));
    h.z = bf16_rne(v.z); l.z = bf16_rne(v.z - bf16_to_f(h.z));
    h.w = bf16_rne(v.w); l.w = bf16_rne(v.w - bf16_to_f(h.w));
    ((ushort4*)hi)[i] = h;
    ((ushort4*)lo)[i] = l;
}

// ---------------------------------------------------------------------------
// K1: Wp row o = mag[o]/||W[o,:]+Bm[o,:]@A|| * (...). fp32 out (round-3
// numerics, q/k path) + bf16 hi/lo out (V MFMA projection).
// ---------------------------------------------------------------------------
__global__ __launch_bounds__(256) void build_wp_k(
    const float* __restrict__ W, const float* __restrict__ A,
    const float* __restrict__ Bm, const float* __restrict__ mag,
    float* __restrict__ Wp, unsigned short* __restrict__ wph,
    unsigned short* __restrict__ wpl)
{
    __shared__ float brow[16];
    __shared__ __align__(16) float wd[512];
    __shared__ float red[5];
    int o = blockIdx.x;
    int tid = threadIdx.x;
    if (tid < 16) brow[tid] = Bm[o * 16 + tid];
    __syncthreads();
    float ss = 0.f;
    for (int i = tid; i < 512; i += 256) {
        float acc = W[o * 512 + i];
#pragma unroll
        for (int r = 0; r < 16; ++r) acc = fmaf(brow[r], A[r * 512 + i], acc);
        wd[i] = acc;
        ss = fmaf(acc, acc, ss);
    }
#pragma unroll
    for (int off = 32; off > 0; off >>= 1) ss += __shfl_down(ss, off);
    int lane = tid & 63, wv = tid >> 6;
    if (lane == 0) red[wv] = ss;
    __syncthreads();
    if (tid == 0) red[4] = mag[o] / sqrtf(red[0] + red[1] + red[2] + red[3]);
    __syncthreads();
    float scl = red[4];
    for (int i = tid; i < 512; i += 256) {
        float v = wd[i] * scl;
        Wp[o * 512 + i] = v;
        unsigned short hh = bf16_rne(v);
        wph[o * 512 + i] = hh;
        wpl[o * 512 + i] = bf16_rne(v - bf16_to_f(hh));
    }
}

// ---------------------------------------------------------------------------
// K2: fp32 y = x(8192x512) @ Wp^T, dst in (b,h,n,d); per-tensor absmax.
// 128x64 tile, 8x4 per thread. Per-element k-order is sequential fmaf
// k=0..511 — BIT-IDENTICAL to the round-3/5/7-verified numerics.
// xs column skew t+(t>>3) keeps the 8-wide a-read at <=2-way banks.
// ---------------------------------------------------------------------------
__global__ __launch_bounds__(256) void proj_gemm_k(
    const float* __restrict__ x, const float* __restrict__ Wp,
    float* __restrict__ dst, unsigned int* __restrict__ amaxp, int do_amax)
{
    __shared__ __align__(16) float xs[16][148];   // [k][t + t/8 skew]
    __shared__ __align__(16) float wsb[16][68];
    __shared__ float redmax[4];
    int tid = threadIdx.x;
    int tx = tid & 15, ty = tid >> 4;
    int t0 = blockIdx.x * 128, o0 = blockIdx.y * 64;
    float acc[8][4];
#pragma unroll
    for (int i = 0; i < 8; ++i)
#pragma unroll
        for (int j = 0; j < 4; ++j) acc[i][j] = 0.f;

    int rw = tid >> 2, c4 = tid & 3;
    int colA = rw + (rw >> 3);                 // skewed col for t = rw
    int colB = (64 + rw) + ((64 + rw) >> 3);   // skewed col for t = 64+rw
    int a0c = ty * 8 + ty;                     // skewed col of t = ty*8 (4 consec)
    int a1c = ty * 8 + 4 + ty;                 // skewed col of t = ty*8+4

    for (int k0 = 0; k0 < 512; k0 += 16) {
        float4 xv0 = *(const float4*)(x + (size_t)(t0 + rw) * 512 + k0 + c4 * 4);
        float4 xv1 = *(const float4*)(x + (size_t)(t0 + 64 + rw) * 512 + k0 + c4 * 4);
        float4 wv = *(const float4*)(Wp + (size_t)(o0 + rw) * 512 + k0 + c4 * 4);
        xs[c4 * 4 + 0][colA] = xv0.x; xs[c4 * 4 + 1][colA] = xv0.y;
        xs[c4 * 4 + 2][colA] = xv0.z; xs[c4 * 4 + 3][colA] = xv0.w;
        xs[c4 * 4 + 0][colB] = xv1.x; xs[c4 * 4 + 1][colB] = xv1.y;
        xs[c4 * 4 + 2][colB] = xv1.z; xs[c4 * 4 + 3][colB] = xv1.w;
        wsb[c4 * 4 + 0][rw] = wv.x; wsb[c4 * 4 + 1][rw] = wv.y;
        wsb[c4 * 4 + 2][rw] = wv.z; wsb[c4 * 4 + 3][rw] = wv.w;
        __syncthreads();
#pragma unroll
        for (int kk = 0; kk < 16; ++kk) {
            float4 b = *(const float4*)&wsb[kk][tx * 4];
            float4 a0 = *(const float4*)&xs[kk][a0c];
            float4 a1 = *(const float4*)&xs[kk][a1c];
            float av[8] = {a0.x, a0.y, a0.z, a0.w, a1.x, a1.y, a1.z, a1.w};
            float bv[4] = {b.x, b.y, b.z, b.w};
#pragma unroll
            for (int i = 0; i < 8; ++i)
#pragma unroll
                for (int j = 0; j < 4; ++j)
                    acc[i][j] = fmaf(av[i], bv[j], acc[i][j]);
        }
        __syncthreads();
    }

    int h = o0 >> 6;
    float mx = 0.f;
#pragma unroll
    for (int i = 0; i < 8; ++i) {
        int t = t0 + ty * 8 + i;
        int b = t >> 10, n = t & 1023;
        float4 v4 = make_float4(acc[i][0], acc[i][1], acc[i][2], acc[i][3]);
        *(float4*)(dst + ((size_t)(b * 8 + h) * 1024 + n) * 64 + tx * 4) = v4;
        mx = fmaxf(mx, fmaxf(fmaxf(fabsf(v4.x), fabsf(v4.y)),
                             fmaxf(fabsf(v4.z), fabsf(v4.w))));
    }
    if (do_amax) {
#pragma unroll
        for (int off = 32; off > 0; off >>= 1) mx = fmaxf(mx, __shfl_down(mx, off));
        if ((tid & 63) == 0) redmax[tid >> 6] = mx;
        __syncthreads();
        if (tid == 0) {
            float m2 = fmaxf(fmaxf(redmax[0], redmax[1]), fmaxf(redmax[2], redmax[3]));
            atomicMax(amaxp, __float_as_uint(m2));
        }
    }
}

// ---------------------------------------------------------------------------
// K2v: MFMA projection (V ONLY — not boundary-sensitive). bf16 hi/lo, 4 MFMAs.
// ---------------------------------------------------------------------------
__global__ __launch_bounds__(256) void proj_mfma_k(
    const unsigned short* __restrict__ xh, const unsigned short* __restrict__ xl,
    const unsigned short* __restrict__ wph, const unsigned short* __restrict__ wpl,
    float* __restrict__ dst)
{
    int tid = threadIdx.x;
    int lane = tid & 63, w = tid >> 6;
    int m_ = lane & 15, quad = lane >> 4;
    int rowA = blockIdx.y * 64 + w * 16 + m_;
    int col0 = blockIdx.x * 64;
    const unsigned short* xhp = xh + (size_t)rowA * 512;
    const unsigned short* xlp = xl + (size_t)rowA * 512;
    floatx4 acc[4];
#pragma unroll
    for (int s = 0; s < 4; ++s) acc[s] = (floatx4){0.f, 0.f, 0.f, 0.f};

    for (int kk = 0; kk < 16; ++kk) {
        int ko = kk * 32 + quad * 8;
        short8 Ah = *(const short8*)(xhp + ko);
        short8 Al = *(const short8*)(xlp + ko);
#pragma unroll
        for (int s = 0; s < 4; ++s) {
            size_t wb = (size_t)(col0 + s * 16 + m_) * 512 + ko;
            short8 Bh = *(const short8*)(wph + wb);
            short8 Bl = *(const short8*)(wpl + wb);
            acc[s] = __builtin_amdgcn_mfma_f32_16x16x32_bf16(Ah, Bh, acc[s], 0, 0, 0);
            acc[s] = __builtin_amdgcn_mfma_f32_16x16x32_bf16(Al, Bh, acc[s], 0, 0, 0);
            acc[s] = __builtin_amdgcn_mfma_f32_16x16x32_bf16(Ah, Bl, acc[s], 0, 0, 0);
            acc[s] = __builtin_amdgcn_mfma_f32_16x16x32_bf16(Al, Bl, acc[s], 0, 0, 0);
        }
    }

    int h = blockIdx.x;
#pragma unroll
    for (int s = 0; s < 4; ++s)
#pragma unroll
        for (int r = 0; r < 4; ++r) {
            int t = blockIdx.y * 64 + w * 16 + quad * 4 + r;
            int bb = t >> 10, n = t & 1023;
            dst[((size_t)(bb * 8 + h) * 1024 + n) * 64 + s * 16 + m_] = acc[s][r];
        }
}

// ---------------------------------------------------------------------------
// K2b: raw fp32 -> int8 levels stored as exact bf16 (for MFMA operands)
// ---------------------------------------------------------------------------
__global__ __launch_bounds__(256) void quant_levels_k(
    const float* __restrict__ raw, const unsigned int* __restrict__ amaxp,
    unsigned short* __restrict__ lv, int n4)
{
    float scale = fmaxf(__uint_as_float(*amaxp) / 127.f, 1e-8f);
    int i = blockIdx.x * 256 + threadIdx.x;
    if (i >= n4) return;
    float4 v = ((const float4*)raw)[i];
    float l0 = fminf(fmaxf(rintf(v.x / scale), -127.f), 127.f);
    float l1 = fminf(fmaxf(rintf(v.y / scale), -127.f), 127.f);
    float l2 = fminf(fmaxf(rintf(v.z / scale), -127.f), 127.f);
    float l3 = fminf(fmaxf(rintf(v.w / scale), -127.f), 127.f);
    ushort4 o;
    o.x = bf16_exact(l0); o.y = bf16_exact(l1);
    o.z = bf16_exact(l2); o.w = bf16_exact(l3);
    ((ushort4*)lv)[i] = o;
}

// ---------------------------------------------------------------------------
// K2c: v (bh,n,64) fp32 -> transposed SINGLE bf16 (bh,d=64,m=1024).
// ---------------------------------------------------------------------------
__global__ __launch_bounds__(256) void vtrans_k(
    const float* __restrict__ vb, unsigned short* __restrict__ vt)
{
    __shared__ float ls[64][69];
    int tid = threadIdx.x;
    int mt = blockIdx.x, bh = blockIdx.y;
#pragma unroll
    for (int l = 0; l < 4; ++l) {
        int idx = l * 256 + tid;
        int r = idx >> 4, c4 = idx & 15;
        float4 v = *(const float4*)(vb + (size_t)(bh * 1024 + mt * 64 + r) * 64 + c4 * 4);
        ls[r][c4 * 4 + 0] = v.x; ls[r][c4 * 4 + 1] = v.y;
        ls[r][c4 * 4 + 2] = v.z; ls[r][c4 * 4 + 3] = v.w;
    }
    __syncthreads();
#pragma unroll
    for (int l = 0; l < 4; ++l) {
        int idx = l * 256 + tid;
        int d = idx >> 4, mg = idx & 15;
        ushort4 hi;
        hi.x = bf16_rne(ls[mg * 4 + 0][d]);
        hi.y = bf16_rne(ls[mg * 4 + 1][d]);
        hi.z = bf16_rne(ls[mg * 4 + 2][d]);
        hi.w = bf16_rne(ls[mg * 4 + 3][d]);
        *(ushort4*)(vt + (size_t)(bh * 64 + d) * 1024 + mt * 64 + mg * 4) = hi;
    }
}

// ---------------------------------------------------------------------------
// K3a: barrier-free MFMA scores + bitmask + online (m,l) over a column
// QUARTER (256 cols). Grid (16 qt, 64 bh, 4 quarter) -> 16384 waves.
// ---------------------------------------------------------------------------
__global__ __launch_bounds__(256) void attn_stats_k(
    const unsigned short* __restrict__ qlv, const unsigned short* __restrict__ klv,
    const unsigned long long* __restrict__ bm, const unsigned int* __restrict__ amax,
    float2* __restrict__ psums)
{
    int tid = threadIdx.x;
    int lane = tid & 63, w = tid >> 6;
    int m_ = lane & 15, quad = lane >> 4;
    int qt = blockIdx.x, bh = blockIdx.y, qtr = blockIdx.z;
    int b = bh >> 3;
    int rowbase = qt * 64 + w * 16;
    float sq = fmaxf(__uint_as_float(amax[0]) / 127.f, 1e-8f);
    float sk = fmaxf(__uint_as_float(amax[1]) / 127.f, 1e-8f);
    float ss = sq * sk;

    const unsigned short* qp = qlv + ((size_t)bh * 1024 + rowbase + m_) * 64;
    short8 Aq0 = *(const short8*)(qp + quad * 8);
    short8 Aq1 = *(const short8*)(qp + 32 + quad * 8);
    const unsigned short* kbase = klv + (size_t)bh * 1024 * 64;
    const unsigned long long* bmb = bm + ((size_t)b * 1024 + rowbase) * 16;

    float mrun[4], lrun[4];
#pragma unroll
    for (int r = 0; r < 4; ++r) { mrun[r] = -1e9f; lrun[r] = 0.f; }

    for (int ci = 0; ci < 4; ++ci) {
        int c = qtr * 4 + ci;
        unsigned long long mk[4];
#pragma unroll
        for (int r = 0; r < 4; ++r) mk[r] = bmb[(quad * 4 + r) * 16 + c];
        float sv[4][4];
#pragma unroll
        for (int s = 0; s < 4; ++s) {
            const unsigned short* kp = kbase + (size_t)(c * 64 + s * 16 + m_) * 64;
            short8 B0 = *(const short8*)(kp + quad * 8);
            short8 B1 = *(const short8*)(kp + 32 + quad * 8);
            floatx4 Cv = {0.f, 0.f, 0.f, 0.f};
            Cv = __builtin_amdgcn_mfma_f32_16x16x32_bf16(Aq0, B0, Cv, 0, 0, 0);
            Cv = __builtin_amdgcn_mfma_f32_16x16x32_bf16(Aq1, B1, Cv, 0, 0, 0);
            int colbit = s * 16 + m_;
#pragma unroll
            for (int r = 0; r < 4; ++r)
                sv[r][s] = ((mk[r] >> colbit) & 1ull) ? Cv[r] * ss : -1e9f;
        }
#pragma unroll
        for (int r = 0; r < 4; ++r) {
            float tm = fmaxf(fmaxf(sv[r][0], sv[r][1]), fmaxf(sv[r][2], sv[r][3]));
            float mn = fmaxf(mrun[r], tm);
            float e = __expf(sv[r][0] - mn) + __expf(sv[r][1] - mn)
                    + __expf(sv[r][2] - mn) + __expf(sv[r][3] - mn);
            lrun[r] = fmaf(lrun[r], __expf(mrun[r] - mn), e);
            mrun[r] = mn;
        }
    }

#pragma unroll
    for (int r = 0; r < 4; ++r) {
        float m = mrun[r], l = lrun[r];
#pragma unroll
        for (int off = 1; off < 16; off <<= 1) {
            float mo = __shfl_xor(m, off);
            float lo = __shfl_xor(l, off);
            float mn = fmaxf(m, mo);
            l = l * __expf(m - mn) + lo * __expf(mo - mn);
            m = mn;
        }
        if (m_ == 0)
            psums[(size_t)qtr * 65536 + (size_t)bh * 1024 + rowbase + quad * 4 + r] =
                make_float2(m, l);
    }
}

// ---------------------------------------------------------------------------
// K3a2: merge 4 quarter-(m,l) into rowstats; global attn amax = max 1/l.
// ---------------------------------------------------------------------------
__global__ __launch_bounds__(256) void stats_merge_k(
    const float2* __restrict__ ps, float2* __restrict__ rowstats,
    unsigned int* __restrict__ amax_attn)
{
    int row = blockIdx.x * 256 + threadIdx.x;        // 65536 rows
    float2 a = ps[row];
    float m = a.x, l = a.y;
#pragma unroll
    for (int q = 1; q < 4; ++q) {
        float2 bq = ps[(size_t)q * 65536 + row];
        float mn = fmaxf(m, bq.x);
        l = l * __expf(m - mn) + bq.y * __expf(bq.x - mn);
        m = mn;
    }
    rowstats[row] = make_float2(m, l);
    float inv = 1.0f / l;
#pragma unroll
    for (int off = 1; off < 64; off <<= 1) inv = fmaxf(inv, __shfl_xor(inv, off));
    if ((threadIdx.x & 63) == 0) atomicMax(amax_attn, __float_as_uint(inv));
}

// ---------------------------------------------------------------------------
// K3b: recompute scores (bit-identical), quantize attn (coalesced float4
// writes from LDS), fused P@V via MFMA. TWO k-tiles per iteration with a
// single lgkm drain per pair (halves the serializing LDS round-trips);
// PV accumulation order per acc unchanged (c0f0,c0f1,c1f0,c1f1 == old ci
// order) -> bit-identical output. Column-HALF split (z=2), out via atomicAdd.
// ---------------------------------------------------------------------------
__global__ __launch_bounds__(256) void attn_out_k(
    const unsigned short* __restrict__ qlv, const unsigned short* __restrict__ klv,
    const unsigned short* __restrict__ vt,
    const unsigned long long* __restrict__ bm, const unsigned int* __restrict__ amax,
    const float2* __restrict__ rowstats,
    float* __restrict__ attn, float* __restrict__ out)
{
    __shared__ unsigned short pl[4][2][16][68];      // [wave][pair-slot][row][col]
    int tid = threadIdx.x;
    int lane = tid & 63, w = tid >> 6;
    int m_ = lane & 15, quad = lane >> 4;
    int qt = blockIdx.x, bh = blockIdx.y, half = blockIdx.z;
    int b = bh >> 3, h = bh & 7;
    int rowbase = qt * 64 + w * 16;
    float sq = fmaxf(__uint_as_float(amax[0]) / 127.f, 1e-8f);
    float sk = fmaxf(__uint_as_float(amax[1]) / 127.f, 1e-8f);
    float ss = sq * sk;
    float sa = fmaxf(__uint_as_float(amax[2]) / 127.f, 1e-8f);
    float inv_sa = 1.0f / sa;

    const unsigned short* qp = qlv + ((size_t)bh * 1024 + rowbase + m_) * 64;
    short8 Aq0 = *(const short8*)(qp + quad * 8);
    short8 Aq1 = *(const short8*)(qp + 32 + quad * 8);
    const unsigned short* kbase = klv + (size_t)bh * 1024 * 64;
    const unsigned long long* bmb = bm + ((size_t)b * 1024 + rowbase) * 16;

    float mrow[4], rlr[4];
#pragma unroll
    for (int r = 0; r < 4; ++r) {
        float2 st = rowstats[(size_t)bh * 1024 + rowbase + quad * 4 + r];
        mrow[r] = st.x;
        rlr[r] = 1.0f / st.y;
    }
    floatx4 acc[4];
#pragma unroll
    for (int r = 0; r < 4; ++r) acc[r] = (floatx4){0.f, 0.f, 0.f, 0.f};

    float* attn_b = attn + ((size_t)bh << 20);

    for (int cp = 0; cp < 4; ++cp) {
        int c0 = half * 8 + cp * 2;
        int c1 = c0 + 1;
        unsigned long long mk0[4], mk1[4];
#pragma unroll
        for (int r = 0; r < 4; ++r) {
            mk0[r] = bmb[(quad * 4 + r) * 16 + c0];
            mk1[r] = bmb[(quad * 4 + r) * 16 + c1];
        }
        unsigned short* plw0 = &pl[w][0][0][0];
        unsigned short* plw1 = &pl[w][1][0][0];
        // ---- tile c0 scores -> pl[w][0]
#pragma unroll
        for (int s = 0; s < 4; ++s) {
            const unsigned short* kp = kbase + (size_t)(c0 * 64 + s * 16 + m_) * 64;
            short8 B0 = *(const short8*)(kp + quad * 8);
            short8 B1 = *(const short8*)(kp + 32 + quad * 8);
            floatx4 Cv = {0.f, 0.f, 0.f, 0.f};
            Cv = __builtin_amdgcn_mfma_f32_16x16x32_bf16(Aq0, B0, Cv, 0, 0, 0);
            Cv = __builtin_amdgcn_mfma_f32_16x16x32_bf16(Aq1, B1, Cv, 0, 0, 0);
            int colbit = s * 16 + m_;
#pragma unroll
            for (int r = 0; r < 4; ++r) {
                float sval = ((mk0[r] >> colbit) & 1ull) ? Cv[r] * ss : -1e9f;
                float p = __expf(sval - mrow[r]) * rlr[r];
                float lv = fminf(rintf(p * inv_sa), 127.f);
                plw0[(quad * 4 + r) * 68 + colbit] = bf16_exact(lv);
            }
        }
        // V fragments for c0 (independent; overlap c1's score phase)
        short8 V00[4], V01[4];
#pragma unroll
        for (int dt = 0; dt < 4; ++dt) {
            const unsigned short* vp = vt + ((size_t)(bh * 64 + dt * 16 + m_)) * 1024 + c0 * 64;
            V00[dt] = *(const short8*)(vp + quad * 8);
            V01[dt] = *(const short8*)(vp + 32 + quad * 8);
        }
        // ---- tile c1 scores -> pl[w][1]
#pragma unroll
        for (int s = 0; s < 4; ++s) {
            const unsigned short* kp = kbase + (size_t)(c1 * 64 + s * 16 + m_) * 64;
            short8 B0 = *(const short8*)(kp + quad * 8);
            short8 B1 = *(const short8*)(kp + 32 + quad * 8);
            floatx4 Cv = {0.f, 0.f, 0.f, 0.f};
            Cv = __builtin_amdgcn_mfma_f32_16x16x32_bf16(Aq0, B0, Cv, 0, 0, 0);
            Cv = __builtin_amdgcn_mfma_f32_16x16x32_bf16(Aq1, B1, Cv, 0, 0, 0);
            int colbit = s * 16 + m_;
#pragma unroll
            for (int r = 0; r < 4; ++r) {
                float sval = ((mk1[r] >> colbit) & 1ull) ? Cv[r] * ss : -1e9f;
                float p = __expf(sval - mrow[r]) * rlr[r];
                float lv = fminf(rintf(p * inv_sa), 127.f);
                plw1[(quad * 4 + r) * 68 + colbit] = bf16_exact(lv);
            }
        }
        short8 V10[4], V11[4];
#pragma unroll
        for (int dt = 0; dt < 4; ++dt) {
            const unsigned short* vp = vt + ((size_t)(bh * 64 + dt * 16 + m_)) * 1024 + c1 * 64;
            V10[dt] = *(const short8*)(vp + quad * 8);
            V11[dt] = *(const short8*)(vp + 32 + quad * 8);
        }
        __asm__ volatile("s_waitcnt lgkmcnt(0)" ::: "memory");
        short8 Ap00 = *(const short8*)&pl[w][0][m_][quad * 8];
        short8 Ap01 = *(const short8*)&pl[w][0][m_][32 + quad * 8];
        short8 Ap10 = *(const short8*)&pl[w][1][m_][quad * 8];
        short8 Ap11 = *(const short8*)&pl[w][1][m_][32 + quad * 8];
#pragma unroll
        for (int dt = 0; dt < 4; ++dt) {
            acc[dt] = __builtin_amdgcn_mfma_f32_16x16x32_bf16(Ap00, V00[dt], acc[dt], 0, 0, 0);
            acc[dt] = __builtin_amdgcn_mfma_f32_16x16x32_bf16(Ap01, V01[dt], acc[dt], 0, 0, 0);
            acc[dt] = __builtin_amdgcn_mfma_f32_16x16x32_bf16(Ap10, V10[dt], acc[dt], 0, 0, 0);
            acc[dt] = __builtin_amdgcn_mfma_f32_16x16x32_bf16(Ap11, V11[dt], acc[dt], 0, 0, 0);
        }
        // coalesced attn writes for both tiles (b64 LDS read -> float4 store)
#pragma unroll
        for (int it = 0; it < 4; ++it) {
            int rrow = it * 4 + quad, col = m_ * 4;
            uint2 pk0 = *(const uint2*)&pl[w][0][rrow][col];
            uint2 pk1 = *(const uint2*)&pl[w][1][rrow][col];
            float4 a0, a1;
            a0.x = bf16_to_f((unsigned short)(pk0.x & 0xffff)) * sa;
            a0.y = bf16_to_f((unsigned short)(pk0.x >> 16)) * sa;
            a0.z = bf16_to_f((unsigned short)(pk0.y & 0xffff)) * sa;
            a0.w = bf16_to_f((unsigned short)(pk0.y >> 16)) * sa;
            a1.x = bf16_to_f((unsigned short)(pk1.x & 0xffff)) * sa;
            a1.y = bf16_to_f((unsigned short)(pk1.x >> 16)) * sa;
            a1.z = bf16_to_f((unsigned short)(pk1.y & 0xffff)) * sa;
            a1.w = bf16_to_f((unsigned short)(pk1.y >> 16)) * sa;
            size_t rbase = ((size_t)(rowbase + rrow)) << 10;
            *(float4*)(attn_b + rbase + c0 * 64 + col) = a0;
            *(float4*)(attn_b + rbase + c1 * 64 + col) = a1;
        }
    }
#pragma unroll
    for (int dt = 0; dt < 4; ++dt)
#pragma unroll
        for (int r = 0; r < 4; ++r) {
            int n = rowbase + quad * 4 + r;
            int d = dt * 16 + m_;
            atomicAdd(&out[(size_t)(b * 1024 + n) * 512 + h * 64 + d], acc[dt][r] * sa);
        }
}

// ---------------------------------------------------------------------------
extern "C" void kernel_launch(void* const* d_in, const int* in_sizes, int n_in,
                              void* d_out, int out_size, void* d_ws, size_t ws_size,
                              hipStream_t stream)
{
    (void)in_sizes; (void)n_in; (void)out_size; (void)ws_size;
    const float* x   = (const float*)d_in[0];
    const int*   adj = (const int*)d_in[1];
    const float* W_q = (const float*)d_in[2];
    const float* A_q = (const float*)d_in[3];
    const float* B_q = (const float*)d_in[4];
    const float* m_q = (const float*)d_in[5];
    const float* W_k = (const float*)d_in[6];
    const float* A_k = (const float*)d_in[7];
    const float* B_k = (const float*)d_in[8];
    const float* m_k = (const float*)d_in[9];
    const float* W_v = (const float*)d_in[10];
    const float* A_v = (const float*)d_in[11];
    const float* B_v = (const float*)d_in[12];
    const float* m_v = (const float*)d_in[13];

    char* ws = (char*)d_ws;
    unsigned short* xh  = (unsigned short*)(ws + OB_XH);
    unsigned short* xl  = (unsigned short*)(ws + OB_XL);
    float* wp           = (float*)(ws + OB_WP);
    unsigned short* wph = (unsigned short*)(ws + OB_WPH);
    unsigned short* wpl = (unsigned short*)(ws + OB_WPL);
    float* raw          = (float*)(ws + OB_RAW);
    unsigned short* qlv = (unsigned short*)(ws + OB_QLV);
    unsigned short* klv = (unsigned short*)(ws + OB_KLV);
    unsigned short* vt  = (unsigned short*)(ws + OB_XH);   // overlays x hi
    float2* rowstats    = (float2*)(ws + OB_RS);
    float2* psums       = (float2*)(ws + OB_PS);           // overlays raw
    unsigned long long* bmask = (unsigned long long*)(ws + OB_BM);
    unsigned int* amax  = (unsigned int*)(ws + OB_AMAX);

    float* out_base  = (float*)d_out;          // (b, n, 512)
    float* attn_base = out_base + 4194304;     // (b, h, n, m)

    hipMemsetAsync(amax, 0, 16, stream);
    hipMemsetAsync(out_base, 0, 16777216, stream);   // out accumulated via atomics

    adj_bits_k<<<32768, 256, 0, stream>>>(adj, bmask);
    split_hl_k<<<4096, 256, 0, stream>>>(x, xh, xl, 1048576);

    // Q (fp32 projection — round-3/5/7 numerics, retiled 128x64)
    build_wp_k<<<512, 256, 0, stream>>>(W_q, A_q, B_q, m_q, wp, wph, wpl);
    proj_gemm_k<<<dim3(64, 8), 256, 0, stream>>>(x, wp, raw, amax + 0, 1);
    quant_levels_k<<<4096, 256, 0, stream>>>(raw, amax + 0, qlv, 1048576);
    // K (fp32 projection)
    build_wp_k<<<512, 256, 0, stream>>>(W_k, A_k, B_k, m_k, wp, wph, wpl);
    proj_gemm_k<<<dim3(64, 8), 256, 0, stream>>>(x, wp, raw, amax + 1, 1);
    quant_levels_k<<<4096, 256, 0, stream>>>(raw, amax + 1, klv, 1048576);
    // V (MFMA hi/lo projection; vtrans overlays x-hi, dead after this proj)
    build_wp_k<<<512, 256, 0, stream>>>(W_v, A_v, B_v, m_v, wp, wph, wpl);
    proj_mfma_k<<<dim3(8, 128), 256, 0, stream>>>(xh, xl, wph, wpl, raw);
    vtrans_k<<<dim3(16, 64), 256, 0, stream>>>(raw, vt);

    attn_stats_k<<<dim3(16, 64, 4), 256, 0, stream>>>(qlv, klv, bmask, amax, psums);
    stats_merge_k<<<256, 256, 0, stream>>>(psums, rowstats, amax + 2);
    attn_out_k<<<dim3(16, 64, 2), 256, 0, stream>>>(qlv, klv, vt, bmask, amax,
                                                    rowstats, attn_base, out_base);
}

// Round 9
// 739.900 us; speedup vs baseline: 1.0644x; 1.0644x over previous
//
#include <hip/hip_runtime.h>
#include <math.h>

// Problem constants: B=8, N=1024, FIN=FOUT=512, H=8, HD=64, BH=64

typedef __attribute__((ext_vector_type(8))) short short8;    // 8 bf16 (4 VGPRs)
typedef __attribute__((ext_vector_type(4))) float floatx4;   // MFMA C/D

// Workspace byte offsets (~82 MB; psums overlay qraw, dead by then)
#define OB_WP    0ull          // 3145728  W' fp32, 1536x512 (q,k,v stacked)
#define OB_QRAW  3145728ull    // 16777216 q raw fp32 (b,h,n,d)
#define OB_PS    OB_QRAW       // 2097152  partial (m,l) x4 (overlays dead qraw)
#define OB_KRAW  19922944ull   // 16777216 k raw fp32
#define OB_VRAW  36700160ull   // 16777216 v raw fp32
#define OB_QLV   53477376ull   // 8388608  q levels bf16
#define OB_KLV   61865984ull   // 8388608  k levels bf16
#define OB_VT    70254592ull   // 8388608  v^T bf16 [bh][d][m]
#define OB_RS    78643200ull   // 524288   rowstats float2
#define OB_BM    79167488ull   // 1048576  adj bitmask u64
#define OB_AMAX  80216064ull   // 16       amax_q, amax_k, amax_attn

__device__ __forceinline__ unsigned short bf16_rne(float f) {
    unsigned int u = __float_as_uint(f);
    unsigned int r = u + 0x7fffu + ((u >> 16) & 1u);
    return (unsigned short)(r >> 16);
}
__device__ __forceinline__ float bf16_to_f(unsigned short h) {
    return __uint_as_float(((unsigned int)h) << 16);
}
// exact for values already representable in bf16 (integer levels |x|<=127)
__device__ __forceinline__ unsigned short bf16_exact(float f) {
    return (unsigned short)(__float_as_uint(f) >> 16);
}

__device__ __forceinline__ void outer4(float (&acc)[4][4], float4 a, float4 b) {
    float av[4] = {a.x, a.y, a.z, a.w};
    float bv[4] = {b.x, b.y, b.z, b.w};
#pragma unroll
    for (int i = 0; i < 4; ++i)
#pragma unroll
        for (int j = 0; j < 4; ++j)
            acc[i][j] = fmaf(av[i], bv[j], acc[i][j]);
}

// ---------------------------------------------------------------------------
// K0: adjacency (8,1024,1024) i32 -> bitmask (8,1024,16) u64. One word/wave.
// ---------------------------------------------------------------------------
__global__ __launch_bounds__(256) void adj_bits_k(
    const int* __restrict__ adj, unsigned long long* __restrict__ bm)
{
    int tid = threadIdx.x;
    int wv = tid >> 6, lane = tid & 63;
    size_t word = (size_t)blockIdx.x * 4 + wv;       // 131072 words total
    int a = adj[word * 64 + lane];
    unsigned long long m = __ballot(a != 0);
    if (lane == 0) bm[word] = m;
}

// ---------------------------------------------------------------------------
// K1: all three DoRA-merged weights in one launch. blockIdx.y selects q/k/v;
// row o of matrix m lands at Wp[(m*512+o)*512 + i]. fp32 only (round-3
// numerics for the whole path now; v is MORE accurate than the old MFMA path).
// ---------------------------------------------------------------------------
__global__ __launch_bounds__(256) void build_wp3_k(
    const float* __restrict__ W_q, const float* __restrict__ A_q,
    const float* __restrict__ B_q, const float* __restrict__ m_q,
    const float* __restrict__ W_k, const float* __restrict__ A_k,
    const float* __restrict__ B_k, const float* __restrict__ m_k,
    const float* __restrict__ W_v, const float* __restrict__ A_v,
    const float* __restrict__ B_v, const float* __restrict__ m_v,
    float* __restrict__ Wp)
{
    __shared__ float brow[16];
    __shared__ __align__(16) float wd[512];
    __shared__ float red[5];
    int o = blockIdx.x;
    int mtx = blockIdx.y;
    const float* W   = mtx == 0 ? W_q : (mtx == 1 ? W_k : W_v);
    const float* A   = mtx == 0 ? A_q : (mtx == 1 ? A_k : A_v);
    const float* Bm  = mtx == 0 ? B_q : (mtx == 1 ? B_k : B_v);
    const float* mag = mtx == 0 ? m_q : (mtx == 1 ? m_k : m_v);
    float* outp = Wp + (size_t)mtx * 262144;
    int tid = threadIdx.x;
    if (tid < 16) brow[tid] = Bm[o * 16 + tid];
    __syncthreads();
    float ss = 0.f;
    for (int i = tid; i < 512; i += 256) {
        float acc = W[o * 512 + i];
#pragma unroll
        for (int r = 0; r < 16; ++r) acc = fmaf(brow[r], A[r * 512 + i], acc);
        wd[i] = acc;
        ss = fmaf(acc, acc, ss);
    }
#pragma unroll
    for (int off = 32; off > 0; off >>= 1) ss += __shfl_down(ss, off);
    int lane = tid & 63, wv = tid >> 6;
    if (lane == 0) red[wv] = ss;
    __syncthreads();
    if (tid == 0) red[4] = mag[o] / sqrtf(red[0] + red[1] + red[2] + red[3]);
    __syncthreads();
    float scl = red[4];
    for (int i = tid; i < 512; i += 256) outp[o * 512 + i] = wd[i] * scl;
}

// ---------------------------------------------------------------------------
// K2: FUSED fp32 projection y = x(8192x512) @ Wp^T(1536x512).
// 64x64 tile, 4x4/thread — per-element sequential-k fmaf, BIT-IDENTICAL to
// the round-3/5/7-verified numerics for q and k. blockIdx.y picks the
// 64-col tile (24 total: q heads 0-7, k heads 8-15, v heads 16-23).
// ---------------------------------------------------------------------------
__global__ __launch_bounds__(256) void proj_gemm_k(
    const float* __restrict__ x, const float* __restrict__ Wp,
    float* __restrict__ qraw, float* __restrict__ kraw, float* __restrict__ vraw,
    unsigned int* __restrict__ amax)
{
    __shared__ __align__(16) float xs[16][68];
    __shared__ __align__(16) float wsb[16][68];
    __shared__ float redmax[4];
    int tid = threadIdx.x;
    int tx = tid & 15, ty = tid >> 4;
    int t0 = blockIdx.x * 64;
    int o0g = blockIdx.y * 64;                 // global output col tile
    int mtx = o0g >> 9;                        // 0=q 1=k 2=v
    int h = (o0g >> 6) & 7;
    float* dst = mtx == 0 ? qraw : (mtx == 1 ? kraw : vraw);
    float acc[4][4];
#pragma unroll
    for (int i = 0; i < 4; ++i)
#pragma unroll
        for (int j = 0; j < 4; ++j) acc[i][j] = 0.f;

    int r = tid >> 2, c4 = tid & 3;
    for (int k0 = 0; k0 < 512; k0 += 16) {
        float4 xv = *(const float4*)(x + (size_t)(t0 + r) * 512 + k0 + c4 * 4);
        float4 wv = *(const float4*)(Wp + (size_t)(o0g + r) * 512 + k0 + c4 * 4);
        xs[c4 * 4 + 0][r] = xv.x; xs[c4 * 4 + 1][r] = xv.y;
        xs[c4 * 4 + 2][r] = xv.z; xs[c4 * 4 + 3][r] = xv.w;
        wsb[c4 * 4 + 0][r] = wv.x; wsb[c4 * 4 + 1][r] = wv.y;
        wsb[c4 * 4 + 2][r] = wv.z; wsb[c4 * 4 + 3][r] = wv.w;
        __syncthreads();
#pragma unroll
        for (int kk = 0; kk < 16; ++kk) {
            float4 a = *(const float4*)&xs[kk][ty * 4];
            float4 b = *(const float4*)&wsb[kk][tx * 4];
            outer4(acc, a, b);
        }
        __syncthreads();
    }

    float mx = 0.f;
#pragma unroll
    for (int i = 0; i < 4; ++i) {
        int t = t0 + ty * 4 + i;
        int b = t >> 10, n = t & 1023;
        float4 v4 = make_float4(acc[i][0], acc[i][1], acc[i][2], acc[i][3]);
        *(float4*)(dst + ((size_t)(b * 8 + h) * 1024 + n) * 64 + tx * 4) = v4;
        mx = fmaxf(mx, fmaxf(fmaxf(fabsf(v4.x), fabsf(v4.y)),
                             fmaxf(fabsf(v4.z), fabsf(v4.w))));
    }
    if (mtx < 2) {
#pragma unroll
        for (int off = 32; off > 0; off >>= 1) mx = fmaxf(mx, __shfl_down(mx, off));
        if ((tid & 63) == 0) redmax[tid >> 6] = mx;
        __syncthreads();
        if (tid == 0) {
            float m2 = fmaxf(fmaxf(redmax[0], redmax[1]), fmaxf(redmax[2], redmax[3]));
            atomicMax(&amax[mtx], __float_as_uint(m2));
        }
    }
}

// ---------------------------------------------------------------------------
// K2b: q AND k raw fp32 -> int8 levels as exact bf16, one launch (grid.y=2).
// ---------------------------------------------------------------------------
__global__ __launch_bounds__(256) void quant2_k(
    const float* __restrict__ qraw, const float* __restrict__ kraw,
    const unsigned int* __restrict__ amax,
    unsigned short* __restrict__ qlv, unsigned short* __restrict__ klv)
{
    int m = blockIdx.y;
    const float* raw = m ? kraw : qraw;
    unsigned short* lv = m ? klv : qlv;
    float scale = fmaxf(__uint_as_float(amax[m]) / 127.f, 1e-8f);
    int i = blockIdx.x * 256 + threadIdx.x;          // n4 = 1048576
    float4 v = ((const float4*)raw)[i];
    float l0 = fminf(fmaxf(rintf(v.x / scale), -127.f), 127.f);
    float l1 = fminf(fmaxf(rintf(v.y / scale), -127.f), 127.f);
    float l2 = fminf(fmaxf(rintf(v.z / scale), -127.f), 127.f);
    float l3 = fminf(fmaxf(rintf(v.w / scale), -127.f), 127.f);
    ushort4 o;
    o.x = bf16_exact(l0); o.y = bf16_exact(l1);
    o.z = bf16_exact(l2); o.w = bf16_exact(l3);
    ((ushort4*)lv)[i] = o;
}

// ---------------------------------------------------------------------------
// K2c: v (bh,n,64) fp32 -> transposed SINGLE bf16 (bh,d=64,m=1024).
// ---------------------------------------------------------------------------
__global__ __launch_bounds__(256) void vtrans_k(
    const float* __restrict__ vb, unsigned short* __restrict__ vt)
{
    __shared__ float ls[64][69];
    int tid = threadIdx.x;
    int mt = blockIdx.x, bh = blockIdx.y;
#pragma unroll
    for (int l = 0; l < 4; ++l) {
        int idx = l * 256 + tid;
        int r = idx >> 4, c4 = idx & 15;
        float4 v = *(const float4*)(vb + (size_t)(bh * 1024 + mt * 64 + r) * 64 + c4 * 4);
        ls[r][c4 * 4 + 0] = v.x; ls[r][c4 * 4 + 1] = v.y;
        ls[r][c4 * 4 + 2] = v.z; ls[r][c4 * 4 + 3] = v.w;
    }
    __syncthreads();
#pragma unroll
    for (int l = 0; l < 4; ++l) {
        int idx = l * 256 + tid;
        int d = idx >> 4, mg = idx & 15;
        ushort4 hi;
        hi.x = bf16_rne(ls[mg * 4 + 0][d]);
        hi.y = bf16_rne(ls[mg * 4 + 1][d]);
        hi.z = bf16_rne(ls[mg * 4 + 2][d]);
        hi.w = bf16_rne(ls[mg * 4 + 3][d]);
        *(ushort4*)(vt + (size_t)(bh * 64 + d) * 1024 + mt * 64 + mg * 4) = hi;
    }
}

// ---------------------------------------------------------------------------
// K3a: barrier-free MFMA scores + bitmask + online (m,l) over a column
// QUARTER (256 cols). Grid (16 qt, 64 bh, 4 quarter) -> 16384 waves.
// ---------------------------------------------------------------------------
__global__ __launch_bounds__(256) void attn_stats_k(
    const unsigned short* __restrict__ qlv, const unsigned short* __restrict__ klv,
    const unsigned long long* __restrict__ bm, const unsigned int* __restrict__ amax,
    float2* __restrict__ psums)
{
    int tid = threadIdx.x;
    int lane = tid & 63, w = tid >> 6;
    int m_ = lane & 15, quad = lane >> 4;
    int qt = blockIdx.x, bh = blockIdx.y, qtr = blockIdx.z;
    int b = bh >> 3;
    int rowbase = qt * 64 + w * 16;
    float sq = fmaxf(__uint_as_float(amax[0]) / 127.f, 1e-8f);
    float sk = fmaxf(__uint_as_float(amax[1]) / 127.f, 1e-8f);
    float ss = sq * sk;

    const unsigned short* qp = qlv + ((size_t)bh * 1024 + rowbase + m_) * 64;
    short8 Aq0 = *(const short8*)(qp + quad * 8);
    short8 Aq1 = *(const short8*)(qp + 32 + quad * 8);
    const unsigned short* kbase = klv + (size_t)bh * 1024 * 64;
    const unsigned long long* bmb = bm + ((size_t)b * 1024 + rowbase) * 16;

    float mrun[4], lrun[4];
#pragma unroll
    for (int r = 0; r < 4; ++r) { mrun[r] = -1e9f; lrun[r] = 0.f; }

    for (int ci = 0; ci < 4; ++ci) {
        int c = qtr * 4 + ci;
        unsigned long long mk[4];
#pragma unroll
        for (int r = 0; r < 4; ++r) mk[r] = bmb[(quad * 4 + r) * 16 + c];
        float sv[4][4];
#pragma unroll
        for (int s = 0; s < 4; ++s) {
            const unsigned short* kp = kbase + (size_t)(c * 64 + s * 16 + m_) * 64;
            short8 B0 = *(const short8*)(kp + quad * 8);
            short8 B1 = *(const short8*)(kp + 32 + quad * 8);
            floatx4 Cv = {0.f, 0.f, 0.f, 0.f};
            Cv = __builtin_amdgcn_mfma_f32_16x16x32_bf16(Aq0, B0, Cv, 0, 0, 0);
            Cv = __builtin_amdgcn_mfma_f32_16x16x32_bf16(Aq1, B1, Cv, 0, 0, 0);
            int colbit = s * 16 + m_;
#pragma unroll
            for (int r = 0; r < 4; ++r)
                sv[r][s] = ((mk[r] >> colbit) & 1ull) ? Cv[r] * ss : -1e9f;
        }
#pragma unroll
        for (int r = 0; r < 4; ++r) {
            float tm = fmaxf(fmaxf(sv[r][0], sv[r][1]), fmaxf(sv[r][2], sv[r][3]));
            float mn = fmaxf(mrun[r], tm);
            float e = __expf(sv[r][0] - mn) + __expf(sv[r][1] - mn)
                    + __expf(sv[r][2] - mn) + __expf(sv[r][3] - mn);
            lrun[r] = fmaf(lrun[r], __expf(mrun[r] - mn), e);
            mrun[r] = mn;
        }
    }

#pragma unroll
    for (int r = 0; r < 4; ++r) {
        float m = mrun[r], l = lrun[r];
#pragma unroll
        for (int off = 1; off < 16; off <<= 1) {
            float mo = __shfl_xor(m, off);
            float lo = __shfl_xor(l, off);
            float mn = fmaxf(m, mo);
            l = l * __expf(m - mn) + lo * __expf(mo - mn);
            m = mn;
        }
        if (m_ == 0)
            psums[(size_t)qtr * 65536 + (size_t)bh * 1024 + rowbase + quad * 4 + r] =
                make_float2(m, l);
    }
}

// ---------------------------------------------------------------------------
// K3a2: merge 4 quarter-(m,l) into rowstats; global attn amax = max 1/l.
// ---------------------------------------------------------------------------
__global__ __launch_bounds__(256) void stats_merge_k(
    const float2* __restrict__ ps, float2* __restrict__ rowstats,
    unsigned int* __restrict__ amax_attn)
{
    int row = blockIdx.x * 256 + threadIdx.x;        // 65536 rows
    float2 a = ps[row];
    float m = a.x, l = a.y;
#pragma unroll
    for (int q = 1; q < 4; ++q) {
        float2 bq = ps[(size_t)q * 65536 + row];
        float mn = fmaxf(m, bq.x);
        l = l * __expf(m - mn) + bq.y * __expf(bq.x - mn);
        m = mn;
    }
    rowstats[row] = make_float2(m, l);
    float inv = 1.0f / l;
#pragma unroll
    for (int off = 1; off < 64; off <<= 1) inv = fmaxf(inv, __shfl_xor(inv, off));
    if ((threadIdx.x & 63) == 0) atomicMax(amax_attn, __float_as_uint(inv));
}

// ---------------------------------------------------------------------------
// K3b: round-7 measured-best version. Recompute scores (bit-identical),
// quantize attn (coalesced float4 writes from LDS), fused P@V via MFMA
// (single-bf16 V, fragments preloaded before the LDS wait); column-HALF
// split (z=2), out combined via fp32 atomicAdd into zeroed out.
// ---------------------------------------------------------------------------
__global__ __launch_bounds__(256) void attn_out_k(
    const unsigned short* __restrict__ qlv, const unsigned short* __restrict__ klv,
    const unsigned short* __restrict__ vt,
    const unsigned long long* __restrict__ bm, const unsigned int* __restrict__ amax,
    const float2* __restrict__ rowstats,
    float* __restrict__ attn, float* __restrict__ out)
{
    __shared__ unsigned short pl[4][2][16][68];      // [wave][dbuf][row][col(+pad)]
    int tid = threadIdx.x;
    int lane = tid & 63, w = tid >> 6;
    int m_ = lane & 15, quad = lane >> 4;
    int qt = blockIdx.x, bh = blockIdx.y, half = blockIdx.z;
    int b = bh >> 3, h = bh & 7;
    int rowbase = qt * 64 + w * 16;
    float sq = fmaxf(__uint_as_float(amax[0]) / 127.f, 1e-8f);
    float sk = fmaxf(__uint_as_float(amax[1]) / 127.f, 1e-8f);
    float ss = sq * sk;
    float sa = fmaxf(__uint_as_float(amax[2]) / 127.f, 1e-8f);
    float inv_sa = 1.0f / sa;

    const unsigned short* qp = qlv + ((size_t)bh * 1024 + rowbase + m_) * 64;
    short8 Aq0 = *(const short8*)(qp + quad * 8);
    short8 Aq1 = *(const short8*)(qp + 32 + quad * 8);
    const unsigned short* kbase = klv + (size_t)bh * 1024 * 64;
    const unsigned long long* bmb = bm + ((size_t)b * 1024 + rowbase) * 16;

    float mrow[4], rlr[4];
#pragma unroll
    for (int r = 0; r < 4; ++r) {
        float2 st = rowstats[(size_t)bh * 1024 + rowbase + quad * 4 + r];
        mrow[r] = st.x;
        rlr[r] = 1.0f / st.y;
    }
    floatx4 acc[4];
#pragma unroll
    for (int r = 0; r < 4; ++r) acc[r] = (floatx4){0.f, 0.f, 0.f, 0.f};

    float* attn_b = attn + ((size_t)bh << 20);

    for (int ci = 0; ci < 8; ++ci) {
        int c = half * 8 + ci;
        // V fragments first: independent of score path, overlap its latency
        short8 Vb0[4], Vb1[4];
#pragma unroll
        for (int dt = 0; dt < 4; ++dt) {
            const unsigned short* vp = vt + ((size_t)(bh * 64 + dt * 16 + m_)) * 1024 + c * 64;
            Vb0[dt] = *(const short8*)(vp + quad * 8);
            Vb1[dt] = *(const short8*)(vp + 32 + quad * 8);
        }
        unsigned long long mk[4];
#pragma unroll
        for (int r = 0; r < 4; ++r) mk[r] = bmb[(quad * 4 + r) * 16 + c];
        unsigned short* plw = &pl[w][ci & 1][0][0];
#pragma unroll
        for (int s = 0; s < 4; ++s) {
            const unsigned short* kp = kbase + (size_t)(c * 64 + s * 16 + m_) * 64;
            short8 B0 = *(const short8*)(kp + quad * 8);
            short8 B1 = *(const short8*)(kp + 32 + quad * 8);
            floatx4 Cv = {0.f, 0.f, 0.f, 0.f};
            Cv = __builtin_amdgcn_mfma_f32_16x16x32_bf16(Aq0, B0, Cv, 0, 0, 0);
            Cv = __builtin_amdgcn_mfma_f32_16x16x32_bf16(Aq1, B1, Cv, 0, 0, 0);
            int colbit = s * 16 + m_;
#pragma unroll
            for (int r = 0; r < 4; ++r) {
                float sval = ((mk[r] >> colbit) & 1ull) ? Cv[r] * ss : -1e9f;
                float p = __expf(sval - mrow[r]) * rlr[r];   // round-3 op order
                float lv = fminf(rintf(p * inv_sa), 127.f);
                plw[(quad * 4 + r) * 68 + colbit] = bf16_exact(lv);
            }
        }
        __asm__ volatile("s_waitcnt lgkmcnt(0)" ::: "memory");
        short8 Ap0 = *(const short8*)&pl[w][ci & 1][m_][quad * 8];
        short8 Ap1 = *(const short8*)&pl[w][ci & 1][m_][32 + quad * 8];
#pragma unroll
        for (int dt = 0; dt < 4; ++dt) {
            acc[dt] = __builtin_amdgcn_mfma_f32_16x16x32_bf16(Ap0, Vb0[dt], acc[dt], 0, 0, 0);
            acc[dt] = __builtin_amdgcn_mfma_f32_16x16x32_bf16(Ap1, Vb1[dt], acc[dt], 0, 0, 0);
        }
        // coalesced attn write: 4 x (b64 LDS read -> float4 store, 256B rows)
#pragma unroll
        for (int it = 0; it < 4; ++it) {
            int rrow = it * 4 + quad, col = m_ * 4;
            uint2 pk = *(const uint2*)&pl[w][ci & 1][rrow][col];
            float4 av;
            av.x = bf16_to_f((unsigned short)(pk.x & 0xffff)) * sa;
            av.y = bf16_to_f((unsigned short)(pk.x >> 16)) * sa;
            av.z = bf16_to_f((unsigned short)(pk.y & 0xffff)) * sa;
            av.w = bf16_to_f((unsigned short)(pk.y >> 16)) * sa;
            *(float4*)(attn_b + (((size_t)(rowbase + rrow)) << 10) + c * 64 + col) = av;
        }
    }
#pragma unroll
    for (int dt = 0; dt < 4; ++dt)
#pragma unroll
        for (int r = 0; r < 4; ++r) {
            int n = rowbase + quad * 4 + r;
            int d = dt * 16 + m_;
            atomicAdd(&out[(size_t)(b * 1024 + n) * 512 + h * 64 + d], acc[dt][r] * sa);
        }
}

// ---------------------------------------------------------------------------
extern "C" void kernel_launch(void* const* d_in, const int* in_sizes, int n_in,
                              void* d_out, int out_size, void* d_ws, size_t ws_size,
                              hipStream_t stream)
{
    (void)in_sizes; (void)n_in; (void)out_size; (void)ws_size;
    const float* x   = (const float*)d_in[0];
    const int*   adj = (const int*)d_in[1];
    const float* W_q = (const float*)d_in[2];
    const float* A_q = (const float*)d_in[3];
    const float* B_q = (const float*)d_in[4];
    const float* m_q = (const float*)d_in[5];
    const float* W_k = (const float*)d_in[6];
    const float* A_k = (const float*)d_in[7];
    const float* B_k = (const float*)d_in[8];
    const float* m_k = (const float*)d_in[9];
    const float* W_v = (const float*)d_in[10];
    const float* A_v = (const float*)d_in[11];
    const float* B_v = (const float*)d_in[12];
    const float* m_v = (const float*)d_in[13];

    char* ws = (char*)d_ws;
    float* wp           = (float*)(ws + OB_WP);
    float* qraw         = (float*)(ws + OB_QRAW);
    float* kraw         = (float*)(ws + OB_KRAW);
    float* vraw         = (float*)(ws + OB_VRAW);
    unsigned short* qlv = (unsigned short*)(ws + OB_QLV);
    unsigned short* klv = (unsigned short*)(ws + OB_KLV);
    unsigned short* vt  = (unsigned short*)(ws + OB_VT);
    float2* rowstats    = (float2*)(ws + OB_RS);
    float2* psums       = (float2*)(ws + OB_PS);           // overlays qraw
    unsigned long long* bmask = (unsigned long long*)(ws + OB_BM);
    unsigned int* amax  = (unsigned int*)(ws + OB_AMAX);

    float* out_base  = (float*)d_out;          // (b, n, 512)
    float* attn_base = out_base + 4194304;     // (b, h, n, m)

    hipMemsetAsync(amax, 0, 16, stream);
    hipMemsetAsync(out_base, 0, 16777216, stream);   // out accumulated via atomics

    adj_bits_k<<<32768, 256, 0, stream>>>(adj, bmask);

    // All three DoRA weights, then one fused projection GEMM (o = 1536)
    build_wp3_k<<<dim3(512, 3), 256, 0, stream>>>(W_q, A_q, B_q, m_q,
                                                  W_k, A_k, B_k, m_k,
                                                  W_v, A_v, B_v, m_v, wp);
    proj_gemm_k<<<dim3(128, 24), 256, 0, stream>>>(x, wp, qraw, kraw, vraw, amax);
    quant2_k<<<dim3(4096, 2), 256, 0, stream>>>(qraw, kraw, amax, qlv, klv);
    vtrans_k<<<dim3(16, 64), 256, 0, stream>>>(vraw, vt);

    attn_stats_k<<<dim3(16, 64, 4), 256, 0, stream>>>(qlv, klv, bmask, amax, psums);
    stats_merge_k<<<256, 256, 0, stream>>>(psums, rowstats, amax + 2);
    attn_out_k<<<dim3(16, 64, 2), 256, 0, stream>>>(qlv, klv, vt, bmask, amax,
                                                    rowstats, attn_base, out_base);
}